// Round 8
// baseline (176.127 us; speedup 1.0000x reference)
//
#include <hip/hip_runtime.h>

// DCT compression: (32,3,512,512) fp32 -> (32,192,64,64) fp32
// Per 8x8 block: coef[a,u] = sum_{y,x} blk[y,x]*C8[a,y]*C8[u,x]
//   C8[u,y] = cos((u+0.5)*PI*y/8), PI = 3.1415 (module's approximation!)
// norm[a,u] = (a==0||u==0) ? sqrt(2)/8 : 0.25   (NOT separable: [0][0]=sqrt2/8)
// out[b, c*64 + z[a*8+u], hb, wb] = coef[a,u]*norm[a,u] / Qtab[c][z[a*8+u]]
//
// History (measured):
//   R4: 64-thr WGs, grid 6144, 1 blk/lane: 62 us, FETCH 50MB WRITE 98MB,
//       Occ 44%, VALU 17%, VGPR 40.
//   R6: 256-thr WGs, grid 1536: 112 us, FETCH/WRITE amplified 2.4x. REVERTED.
//   R7: 2 blk/lane, paired 512B stores, grid 3072: 62-67 us, Occ 23%, VGPR 80.
//       Occupancy halved, same perf -> perf tracks (waves x chains)/CU, i.e.
//       latency-bound on load chains; store pairing neutral; traffic clean.
// Diagnosis: VGPR=40 proves LLVM sank the 16 loads into the consume loop
// (16 in-flight float4 dests alone = 64 VGPRs) -> ~1-2 loads outstanding
// per wave -> ~3.6KB/CU outstanding -> 2.4 TB/s (Little's law), matching
// measurement. Occupancy is NOT the lever; per-wave MLP is.
// This version: R4 geometry + __builtin_amdgcn_sched_barrier(0) between the
// 16-load batch and compute. Loads can't sink, dests stay live (~64 VGPR),
// compiler still auto-inserts fine-grained vmcnt(N) before each use.
// 4x per-wave MLP at unchanged residency (VGPR<=128 keeps 4 waves/SIMD;
// 16-WG/CU cap binds as before).

namespace {

// Compile-time cos: reduce to [-pi,pi] in double, 14-term Taylor (err ~1e-15),
// then round to float. Argument matches the verified device expression:
// ((u+0.5f)*3.1415f)*(y*0.125f).
constexpr double ccos_d(double x) {
    while (x > 3.141592653589793) x -= 6.283185307179586;
    while (x < -3.141592653589793) x += 6.283185307179586;
    const double x2 = x * x;
    double t = 1.0, s = 1.0;
    for (int k = 1; k <= 14; ++k) {
        t *= -x2 / (double)((2 * k - 1) * (2 * k));
        s += t;
    }
    return s;
}

struct Tables {
    float c8[64];      // c8[u*8+y] = cos((u+0.5)*3.1415*y/8); c8[u*8+0] == 1.0f
    float scl[2][64];  // [luma/chroma][a*8+u] = norm(a,u)/Qtab[z(a,u)]
    int   zoff[64];    // z[a*8+u] * 4096 (output element offset)
};

constexpr Tables make_tables() {
    Tables T{};
    for (int u = 0; u < 8; ++u)
        for (int y = 0; y < 8; ++y) {
            const float arg = ((float)u + 0.5f) * 3.1415f * ((float)y * 0.125f);
            T.c8[u * 8 + y] = (float)ccos_d((double)arg);
        }
    // faithful port of reference _zigzag(8); p is the pre-transpose pattern
    int p[64] = {};
    for (int y = 0; y < 8; ++y)
        for (int x = (y & 1); x < 8 - y; x += 2) {
            const int v = x + y + 1;
            p[y * 8 + x] = v * (v + 1) / 2 - x - 1;
        }
    for (int y = 0; y < 8; ++y)
        for (int x = ((y + 1) & 1); x < 8 - y; x += 2) {
            const int v = x + y + 1;
            p[y * 8 + x] = v * (v + 1) / 2 - y - 1;
        }
    for (int y = 7; y >= 0; --y)
        for (int x = 7; x >= 8 - y; --x)
            p[y * 8 + x] = 63 - p[(7 - y) * 8 + (7 - x)];

    // Q=50 -> s=100 -> Q_luma = floor((100*T+50)/100) = T exactly (integers)
    const int QT0[64] = {16,11,10,16,24,40,51,61, 12,12,14,19,26,58,60,55,
                         14,13,16,24,40,57,69,56, 14,17,22,29,51,87,80,62,
                         18,22,37,56,68,109,103,77, 24,35,55,64,81,104,113,92,
                         49,64,78,87,103,121,120,101, 72,92,95,98,112,100,103,99};
    const int QT1[64] = {17,18,24,47,99,99,99,99, 18,21,26,66,99,99,99,99,
                         24,26,56,99,99,99,99,99, 47,66,99,99,99,99,99,99,
                         99,99,99,99,99,99,99,99, 99,99,99,99,99,99,99,99,
                         99,99,99,99,99,99,99,99, 99,99,99,99,99,99,99,99};
    for (int i = 0; i < 64; ++i) {
        const int a = i >> 3, u = i & 7;
        const int zi = p[u * 8 + a];  // z[a*8+u] = p.T[a][u] = p[u*8+a]
        T.zoff[i] = zi << 12;         // * 64*64
        const float nrm = (a == 0 || u == 0) ? 0.17677669529663687f : 0.25f;
        T.scl[0][i] = nrm / (float)QT0[zi];
        T.scl[1][i] = nrm / (float)QT1[zi];
    }
    return T;
}

constexpr Tables TB = make_tables();

}  // namespace

// Grid: 6144 single-wave workgroups.
//   blockIdx.x = bc*64 + hb;  bc = b*3+c in [0,96);  hb in [0,64)
//   lane (threadIdx.x) = wb.  Each lane: one 8x8 block -> 64 outputs.
__global__ __launch_bounds__(64, 4)
void DCTCompression_25786983645730_kernel(const float* __restrict__ x,
                                          float* __restrict__ out) {
    const int idx = blockIdx.x;
    const int hb  = idx & 63;
    const int bc  = idx >> 6;       // b*3 + c
    const int c   = bc % 3;         // wave-uniform
    const int wb  = threadIdx.x;    // 0..63

    // uniform base + 32-bit lane offset -> saddr-form global loads/stores
    const float* xbase = x + (size_t)bc * 262144;
    float*       obase = out + (size_t)bc * 262144;
    const int    xo    = hb * 8 * 512 + wb * 8;
    const int    oo    = hb * 64 + wb;

    // ---- load 8x8 block: 16 independent float4 loads, ALL issued before any
    //      compute (sched_barrier pins them above; dests stay live ~64 VGPR;
    //      compiler still inserts fine-grained vmcnt(N) before each use) ----
    float4 r0[8], r1[8];
#pragma unroll
    for (int y = 0; y < 8; ++y) {
        r0[y] = *reinterpret_cast<const float4*>(xbase + xo + y * 512);
        r1[y] = *reinterpret_cast<const float4*>(xbase + xo + y * 512 + 4);
    }
    __builtin_amdgcn_sched_barrier(0);  // nothing moves across: 16 loads in flight

    // ---- pass 1 (row transform): s[y][u] = sum_x blk[y][x] * C8[u][x] ----
    // consumes r0/r1 row-by-row; s replaces the block in registers
    float s[8][8];
#pragma unroll
    for (int y = 0; y < 8; ++y) {
        const float row[8] = {r0[y].x, r0[y].y, r0[y].z, r0[y].w,
                              r1[y].x, r1[y].y, r1[y].z, r1[y].w};
#pragma unroll
        for (int u = 0; u < 8; ++u) {
            float acc = row[0] * TB.c8[u * 8 + 0];  // c8[u][0]==1.0f -> folds
#pragma unroll
            for (int xx = 1; xx < 8; ++xx)
                acc = fmaf(row[xx], TB.c8[u * 8 + xx], acc);
            s[y][u] = acc;
        }
    }

    // ---- pass 2 (column transform), a-outer; scale + scatter per a ----
#pragma unroll
    for (int a = 0; a < 8; ++a) {
        float acc[8];
#pragma unroll
        for (int u = 0; u < 8; ++u) {
            float v = s[0][u] * TB.c8[a * 8 + 0];   // c8[a][0]==1.0f -> folds
#pragma unroll
            for (int y = 1; y < 8; ++y)
                v = fmaf(s[y][u], TB.c8[a * 8 + y], v);
            acc[u] = v;
        }
#pragma unroll
        for (int u = 0; u < 8; ++u) {
            const int j = a * 8 + u;
            const float sc = (c == 0) ? TB.scl[0][j] : TB.scl[1][j];  // scalar cselect
            obase[oo + TB.zoff[j]] = acc[u] * sc;  // coalesced 256B/wave store
        }
    }
}

extern "C" void kernel_launch(void* const* d_in, const int* in_sizes, int n_in,
                              void* d_out, int out_size, void* d_ws, size_t ws_size,
                              hipStream_t stream) {
    const float* x = (const float*)d_in[0];
    float* out = (float*)d_out;
    // B*C*(H/8) = 32*3*64 = 6144 single-wave workgroups
    DCTCompression_25786983645730_kernel<<<dim3(6144), dim3(64), 0, stream>>>(x, out);
}

// Round 9
// 171.793 us; speedup vs baseline: 1.0252x; 1.0252x over previous
//
#include <hip/hip_runtime.h>

// DCT compression: (32,3,512,512) fp32 -> (32,192,64,64) fp32
// Per 8x8 block: coef[a,u] = sum_{y,x} blk[y,x]*C8[a,y]*C8[u,x]
//   C8[u,y] = cos((u+0.5)*PI*y/8), PI = 3.1415 (module's approximation!)
// norm[a,u] = (a==0||u==0) ? sqrt(2)/8 : 0.25   (NOT separable: [0][0]=sqrt2/8)
// out[b, c*64 + z[a*8+u], hb, wb] = coef[a,u]*norm[a,u] / Qtab[c][z[a*8+u]]
//
// History (measured):
//   R4: 64-thr WGs, grid 6144: 62 us, FETCH 50MB WRITE 98MB, Occ 44%,
//       VALU 17%, VGPR 40.
//   R6: 256-thr WGs: 112 us, traffic amplified 2.4x (fabric moved 3.26 TB/s
//       -> memory system is NOT capped at 2.4). REVERTED.
//   R7: 2 blk/lane, 512B store pairs, Occ 23%: 62-67 us. Same perf at half
//       occupancy -> perf tracks concurrent load-chains, not occupancy.
//   R8: sched_barrier(0) after loads: VGPR STILL 40 -> barrier ineffective
//       (IR-level sinking; 16 live float4 dests would need 64 VGPRs).
//       dur unchanged 64-66 us. The MLP lever was never actually engaged.
// This version: pin via DATA DEPENDENCE. Empty asm volatile with all 16 load
// results as "+v" operands: compiler must issue+complete all 16 loads before
// the asm (it inserts the vmcnt itself), and no use can hoist above it.
// 16 loads (16KB/wave) genuinely in flight -> Little's law gives ~4x the
// outstanding bytes/CU vs the serialized chain. Geometry stays R4.

namespace {

typedef float f32x4 __attribute__((ext_vector_type(4)));

// Compile-time cos: reduce to [-pi,pi] in double, 14-term Taylor (err ~1e-15),
// then round to float. Argument matches the verified device expression:
// ((u+0.5f)*3.1415f)*(y*0.125f).
constexpr double ccos_d(double x) {
    while (x > 3.141592653589793) x -= 6.283185307179586;
    while (x < -3.141592653589793) x += 6.283185307179586;
    const double x2 = x * x;
    double t = 1.0, s = 1.0;
    for (int k = 1; k <= 14; ++k) {
        t *= -x2 / (double)((2 * k - 1) * (2 * k));
        s += t;
    }
    return s;
}

struct Tables {
    float c8[64];      // c8[u*8+y] = cos((u+0.5)*3.1415*y/8); c8[u*8+0] == 1.0f
    float scl[2][64];  // [luma/chroma][a*8+u] = norm(a,u)/Qtab[z(a,u)]
    int   zoff[64];    // z[a*8+u] * 4096 (output element offset)
};

constexpr Tables make_tables() {
    Tables T{};
    for (int u = 0; u < 8; ++u)
        for (int y = 0; y < 8; ++y) {
            const float arg = ((float)u + 0.5f) * 3.1415f * ((float)y * 0.125f);
            T.c8[u * 8 + y] = (float)ccos_d((double)arg);
        }
    // faithful port of reference _zigzag(8); p is the pre-transpose pattern
    int p[64] = {};
    for (int y = 0; y < 8; ++y)
        for (int x = (y & 1); x < 8 - y; x += 2) {
            const int v = x + y + 1;
            p[y * 8 + x] = v * (v + 1) / 2 - x - 1;
        }
    for (int y = 0; y < 8; ++y)
        for (int x = ((y + 1) & 1); x < 8 - y; x += 2) {
            const int v = x + y + 1;
            p[y * 8 + x] = v * (v + 1) / 2 - y - 1;
        }
    for (int y = 7; y >= 0; --y)
        for (int x = 7; x >= 8 - y; --x)
            p[y * 8 + x] = 63 - p[(7 - y) * 8 + (7 - x)];

    // Q=50 -> s=100 -> Q_luma = floor((100*T+50)/100) = T exactly (integers)
    const int QT0[64] = {16,11,10,16,24,40,51,61, 12,12,14,19,26,58,60,55,
                         14,13,16,24,40,57,69,56, 14,17,22,29,51,87,80,62,
                         18,22,37,56,68,109,103,77, 24,35,55,64,81,104,113,92,
                         49,64,78,87,103,121,120,101, 72,92,95,98,112,100,103,99};
    const int QT1[64] = {17,18,24,47,99,99,99,99, 18,21,26,66,99,99,99,99,
                         24,26,56,99,99,99,99,99, 47,66,99,99,99,99,99,99,
                         99,99,99,99,99,99,99,99, 99,99,99,99,99,99,99,99,
                         99,99,99,99,99,99,99,99, 99,99,99,99,99,99,99,99};
    for (int i = 0; i < 64; ++i) {
        const int a = i >> 3, u = i & 7;
        const int zi = p[u * 8 + a];  // z[a*8+u] = p.T[a][u] = p[u*8+a]
        T.zoff[i] = zi << 12;         // * 64*64
        const float nrm = (a == 0 || u == 0) ? 0.17677669529663687f : 0.25f;
        T.scl[0][i] = nrm / (float)QT0[zi];
        T.scl[1][i] = nrm / (float)QT1[zi];
    }
    return T;
}

constexpr Tables TB = make_tables();

}  // namespace

// Grid: 6144 single-wave workgroups.
//   blockIdx.x = bc*64 + hb;  bc = b*3+c in [0,96);  hb in [0,64)
//   lane (threadIdx.x) = wb.  Each lane: one 8x8 block -> 64 outputs.
__global__ __launch_bounds__(64, 4)
void DCTCompression_25786983645730_kernel(const float* __restrict__ x,
                                          float* __restrict__ out) {
    const int idx = blockIdx.x;
    const int hb  = idx & 63;
    const int bc  = idx >> 6;       // b*3 + c
    const int c   = bc % 3;         // wave-uniform
    const int wb  = threadIdx.x;    // 0..63

    // uniform base + 32-bit lane offset -> saddr-form global loads/stores
    const float* xbase = x + (size_t)bc * 262144;
    float*       obase = out + (size_t)bc * 262144;
    const int    xo    = hb * 8 * 512 + wb * 8;
    const int    oo    = hb * 64 + wb;

    // ---- load 8x8 block: 16 independent f32x4 loads ----
    f32x4 r0[8], r1[8];
#pragma unroll
    for (int y = 0; y < 8; ++y) {
        r0[y] = *reinterpret_cast<const f32x4*>(xbase + xo + y * 512);
        r1[y] = *reinterpret_cast<const f32x4*>(xbase + xo + y * 512 + 4);
    }
    // Data-dependence pin: this asm "reads and redefines" all 16 load results,
    // so ALL 16 loads must issue (and complete; compiler inserts the vmcnt)
    // before any FMA can consume them. 16 loads genuinely in flight per wave.
    asm volatile(""
                 : "+v"(r0[0]), "+v"(r0[1]), "+v"(r0[2]), "+v"(r0[3]),
                   "+v"(r0[4]), "+v"(r0[5]), "+v"(r0[6]), "+v"(r0[7]),
                   "+v"(r1[0]), "+v"(r1[1]), "+v"(r1[2]), "+v"(r1[3]),
                   "+v"(r1[4]), "+v"(r1[5]), "+v"(r1[6]), "+v"(r1[7]));

    // ---- pass 1 (row transform): s[y][u] = sum_x blk[y][x] * C8[u][x] ----
    // consumes r0/r1 row-by-row; s replaces the block in registers
    float s[8][8];
#pragma unroll
    for (int y = 0; y < 8; ++y) {
        const float row[8] = {r0[y][0], r0[y][1], r0[y][2], r0[y][3],
                              r1[y][0], r1[y][1], r1[y][2], r1[y][3]};
#pragma unroll
        for (int u = 0; u < 8; ++u) {
            float acc = row[0] * TB.c8[u * 8 + 0];  // c8[u][0]==1.0f -> folds
#pragma unroll
            for (int xx = 1; xx < 8; ++xx)
                acc = fmaf(row[xx], TB.c8[u * 8 + xx], acc);
            s[y][u] = acc;
        }
    }

    // ---- pass 2 (column transform), a-outer; scale + scatter per a ----
#pragma unroll
    for (int a = 0; a < 8; ++a) {
        float acc[8];
#pragma unroll
        for (int u = 0; u < 8; ++u) {
            float v = s[0][u] * TB.c8[a * 8 + 0];   // c8[a][0]==1.0f -> folds
#pragma unroll
            for (int y = 1; y < 8; ++y)
                v = fmaf(s[y][u], TB.c8[a * 8 + y], v);
            acc[u] = v;
        }
#pragma unroll
        for (int u = 0; u < 8; ++u) {
            const int j = a * 8 + u;
            const float sc = (c == 0) ? TB.scl[0][j] : TB.scl[1][j];  // scalar cselect
            obase[oo + TB.zoff[j]] = acc[u] * sc;  // coalesced 256B/wave store
        }
    }
}

extern "C" void kernel_launch(void* const* d_in, const int* in_sizes, int n_in,
                              void* d_out, int out_size, void* d_ws, size_t ws_size,
                              hipStream_t stream) {
    const float* x = (const float*)d_in[0];
    float* out = (float*)d_out;
    // B*C*(H/8) = 32*3*64 = 6144 single-wave workgroups
    DCTCompression_25786983645730_kernel<<<dim3(6144), dim3(64), 0, stream>>>(x, out);
}